// Round 1
// baseline (12528.626 us; speedup 1.0000x reference)
//
#include <hip/hip_runtime.h>
#include <hip/hip_bf16.h>

// ShapeNet DGCNN-ish model, fp32 correctness-first baseline.
// B=8, N=2048, K=32. Workspace layout (floats):
//   sq   : 16384            (B*N)
//   idx  : 524288 ints      (B*N*32)
//   xc   : 3145728          (B,192,N)  f1|f2|f3
//   h    : 16777216         (B,1024,N)
//   q    : 16777216
//   k    : 16777216  (reused as ff1 output (B,512,N) later)
//   S    : 4194304          (N,N) per-batch scratch (dist + attention)
//   total = 58,212,352 floats = 233 MB.  v lives in d_out until final GEMM.

constexpr int Bn  = 8;
constexpr int Np  = 2048;
constexpr int KNN = 32;

// ---------------------------------------------------------------- sq ----
__global__ __launch_bounds__(256)
void sq_kernel(const float* __restrict__ f, long bstride, int C,
               float* __restrict__ out) {
  int i = blockIdx.x * 256 + threadIdx.x;   // over B*N
  int b = i >> 11;
  int n = i & 2047;
  const float* p = f + (long)b * bstride + n;
  float s = 0.f;
  for (int c = 0; c < C; ++c) { float x = p[(long)c * Np]; s += x * x; }
  out[i] = s;
}

// -------------------------------------------------------------- GEMM ----
// C[i][j] = sum_k A[i][k]*B[k][j]  (logical), 128x128 tile, BK=8, 8x8/thread.
// AT: A stored as [k][i] (i contiguous).  BT: B stored as [j][k] (k contiguous).
// Epilogues: dist (sqB: v = sqB[j]-2v), resid (+resid), bn ((v-m)*g*rsqrt(var+eps)+b), lrelu.
template<bool AT, bool BT>
__global__ __launch_bounds__(256)
void gemm_kernel(const float* __restrict__ A, int lda, long sA,
                 const float* __restrict__ B, int ldb, long sB,
                 float* __restrict__ C, int ldc, long sC,
                 int M, int Nc, int Kd,
                 const float* __restrict__ bn,
                 const float* __restrict__ resid,
                 const float* __restrict__ sqB, long sSq,
                 int lrelu) {
  int bz = blockIdx.z;
  A += (long)bz * sA;
  B += (long)bz * sB;
  C += (long)bz * sC;
  if (resid) resid += (long)bz * sC;
  if (sqB)   sqB   += (long)bz * sSq;
  int i0 = blockIdx.y * 128, j0 = blockIdx.x * 128;
  __shared__ float As[8][128];
  __shared__ float Bs[8][128];
  float acc[8][8];
#pragma unroll
  for (int a = 0; a < 8; ++a)
#pragma unroll
    for (int b2 = 0; b2 < 8; ++b2) acc[a][b2] = 0.f;
  int t  = threadIdx.x;
  int tx = t & 15, ty = t >> 4;
  for (int k0 = 0; k0 < Kd; k0 += 8) {
    if (!AT) {
      int ii = t >> 1, kk = (t & 1) * 4;
#pragma unroll
      for (int u = 0; u < 4; ++u) {
        int kg = k0 + kk + u;
        As[kk + u][ii] = (kg < Kd) ? A[(long)(i0 + ii) * lda + kg] : 0.f;
      }
    } else {
      int kk = t >> 5, ii = (t & 31) * 4;
      int kg = k0 + kk;
#pragma unroll
      for (int u = 0; u < 4; ++u)
        As[kk][ii + u] = (kg < Kd) ? A[(long)kg * lda + i0 + ii + u] : 0.f;
    }
    if (!BT) {
      int kk = t >> 5, jj = (t & 31) * 4;
      int kg = k0 + kk;
#pragma unroll
      for (int u = 0; u < 4; ++u)
        Bs[kk][jj + u] = (kg < Kd) ? B[(long)kg * ldb + j0 + jj + u] : 0.f;
    } else {
      int jj = t >> 1, kk = (t & 1) * 4;
#pragma unroll
      for (int u = 0; u < 4; ++u) {
        int kg = k0 + kk + u;
        Bs[kk + u][jj] = (kg < Kd) ? B[(long)(j0 + jj) * ldb + kg] : 0.f;
      }
    }
    __syncthreads();
#pragma unroll
    for (int kk = 0; kk < 8; ++kk) {
      float av[8], bv[8];
#pragma unroll
      for (int u = 0; u < 8; ++u) av[u] = As[kk][ty * 8 + u];
#pragma unroll
      for (int u = 0; u < 8; ++u) bv[u] = Bs[kk][tx * 8 + u];
#pragma unroll
      for (int a = 0; a < 8; ++a)
#pragma unroll
        for (int b2 = 0; b2 < 8; ++b2) acc[a][b2] += av[a] * bv[b2];
    }
    __syncthreads();
  }
#pragma unroll
  for (int a = 0; a < 8; ++a) {
    int i = i0 + ty * 8 + a;
    float gg = 0.f, bb = 0.f, mm = 0.f, sc = 0.f;
    if (bn) {
      gg = bn[i]; bb = bn[M + i]; mm = bn[2 * M + i];
      sc = gg * rsqrtf(bn[3 * M + i] + 1e-5f);
    }
#pragma unroll
    for (int b2 = 0; b2 < 8; ++b2) {
      int j = j0 + tx * 8 + b2;
      float v = acc[a][b2];
      if (sqB)   v = sqB[j] - 2.f * v;
      if (resid) v += resid[(long)i * ldc + j];
      if (bn)    v = (v - mm) * sc + bb;
      if (lrelu) v = (v >= 0.f) ? v : 0.2f * v;
      C[(long)i * ldc + j] = v;
    }
  }
}

// -------------------------------------------------------------- topk ----
// One wave per row: iteratively extract 32 smallest (tie -> lower index).
__global__ __launch_bounds__(64)
void topk_kernel(const float* __restrict__ D, int* __restrict__ idxOut) {
  int n = blockIdx.x;
  const float* row = D + (long)n * Np;
  int lane = threadIdx.x;
  float v[32];
#pragma unroll
  for (int j = 0; j < 32; ++j) v[j] = row[j * 64 + lane];
  unsigned removed = 0u;
  __shared__ int sel[KNN];
  for (int t = 0; t < KNN; ++t) {
    float bk = 3.4e38f; int bi = -1; unsigned bbit = 0u;
#pragma unroll
    for (int j = 0; j < 32; ++j) {
      int m = j * 64 + lane;
      bool live = !(removed & (1u << j));
      bool better = live && ((v[j] < bk) || (v[j] == bk && (unsigned)m < (unsigned)bi));
      if (better) { bk = v[j]; bi = m; bbit = 1u << j; }
    }
    float rk = bk; int ri = bi;
#pragma unroll
    for (int off = 32; off > 0; off >>= 1) {
      float ok = __shfl_xor(rk, off);
      int   oi = __shfl_xor(ri, off);
      if ((ok < rk) || (ok == rk && (unsigned)oi < (unsigned)ri)) { rk = ok; ri = oi; }
    }
    if (bi == ri) removed |= bbit;
    if (lane == 0) sel[t] = ri;
  }
  __syncthreads();
  if (lane < KNN) idxOut[(long)n * KNN + lane] = sel[lane];
}

// ---------------------------------------------------------- edgeconv ----
// One wave per point. h1 = W1a*nbr + sum_c (W1b-W1a)[o,c]*ctr[c]; bn,lrelu;
// h2 = W2*h1; bn,lrelu; max over k.
template<int CIN>
__global__ __launch_bounds__(64)
void edgeconv_kernel(const float* __restrict__ feat, long fbstride,
                     const int* __restrict__ idx,
                     const float* __restrict__ w1,   // 64 x 2*CIN
                     const float* __restrict__ bn1,
                     const float* __restrict__ w2,   // 64 x 64
                     const float* __restrict__ bn2,
                     float* __restrict__ out, long obstride) {
  int n = blockIdx.x, b = blockIdx.y;
  int lane = threadIdx.x;
  const float* f = feat + (long)b * fbstride;
  __shared__ float ctr[CIN];
  __shared__ int   nb[KNN];
  __shared__ float nbr[CIN * KNN];
  __shared__ float h1s[64 * 33];
  if (lane < KNN) nb[lane] = idx[((long)b * Np + n) * KNN + lane];
  if (lane < CIN) ctr[lane] = f[(long)lane * Np + n];
  __syncthreads();
  {
    int k2 = lane & 31;
    int hi = lane >> 5;
    int m = nb[k2];
    constexpr int ITER = (CIN * KNN + 63) / 64;
#pragma unroll
    for (int tt = 0; tt < ITER; ++tt) {
      int c = tt * 2 + hi;
      if (c < CIN) nbr[c * KNN + k2] = f[(long)c * Np + m];
    }
  }
  __syncthreads();
  int o = lane;
  const float* w1r = w1 + o * 2 * CIN;
  float base = 0.f;
#pragma unroll
  for (int c = 0; c < CIN; ++c) base += (w1r[CIN + c] - w1r[c]) * ctr[c];
  float acc[KNN];
#pragma unroll
  for (int k2 = 0; k2 < KNN; ++k2) acc[k2] = base;
  constexpr int CH = (CIN >= 8) ? 8 : CIN;
  for (int c0 = 0; c0 < CIN; c0 += CH) {
    float w[CH];
#pragma unroll
    for (int u = 0; u < CH; ++u) w[u] = w1r[c0 + u];
#pragma unroll
    for (int u = 0; u < CH; ++u)
#pragma unroll
      for (int k2 = 0; k2 < KNN; ++k2) acc[k2] += w[u] * nbr[(c0 + u) * KNN + k2];
  }
  {
    float gg = bn1[o], bb = bn1[64 + o], mm = bn1[128 + o];
    float sc = gg * rsqrtf(bn1[192 + o] + 1e-5f);
#pragma unroll
    for (int k2 = 0; k2 < KNN; ++k2) {
      float x = (acc[k2] - mm) * sc + bb;
      h1s[o * 33 + k2] = (x >= 0.f) ? x : 0.2f * x;
    }
  }
  __syncthreads();
  const float* w2r = w2 + o * 64;
  float a2[KNN];
#pragma unroll
  for (int k2 = 0; k2 < KNN; ++k2) a2[k2] = 0.f;
  for (int c0 = 0; c0 < 64; c0 += 8) {
    float w[8];
#pragma unroll
    for (int u = 0; u < 8; ++u) w[u] = w2r[c0 + u];
#pragma unroll
    for (int u = 0; u < 8; ++u)
#pragma unroll
      for (int k2 = 0; k2 < KNN; ++k2) a2[k2] += w[u] * h1s[(c0 + u) * 33 + k2];
  }
  float gg = bn2[o], bb = bn2[64 + o], mm = bn2[128 + o];
  float sc = gg * rsqrtf(bn2[192 + o] + 1e-5f);
  float mx = -3.4e38f;
#pragma unroll
  for (int k2 = 0; k2 < KNN; ++k2) {
    float x = (a2[k2] - mm) * sc + bb;
    x = (x >= 0.f) ? x : 0.2f * x;
    mx = fmaxf(mx, x);
  }
  out[(long)b * obstride + (long)o * Np + n] = mx;
}

// ----------------------------------------------------------- softmax ----
__global__ __launch_bounds__(256)
void softmax_kernel(float* __restrict__ S) {
  long row = blockIdx.x;
  float* p = S + row * Np;
  int t = threadIdx.x;
  const float scale = 0.03125f;  // 1/sqrt(1024)
  float v[8];
  float mx = -3.4e38f;
#pragma unroll
  for (int u = 0; u < 8; ++u) { v[u] = p[u * 256 + t] * scale; mx = fmaxf(mx, v[u]); }
  __shared__ float red[4];
#pragma unroll
  for (int off = 32; off > 0; off >>= 1) mx = fmaxf(mx, __shfl_xor(mx, off));
  if ((t & 63) == 0) red[t >> 6] = mx;
  __syncthreads();
  mx = fmaxf(fmaxf(red[0], red[1]), fmaxf(red[2], red[3]));
  __syncthreads();
  float sum = 0.f;
#pragma unroll
  for (int u = 0; u < 8; ++u) { v[u] = __expf(v[u] - mx); sum += v[u]; }
#pragma unroll
  for (int off = 32; off > 0; off >>= 1) sum += __shfl_xor(sum, off);
  if ((t & 63) == 0) red[t >> 6] = sum;
  __syncthreads();
  sum = red[0] + red[1] + red[2] + red[3];
  float inv = 1.f / sum;
#pragma unroll
  for (int u = 0; u < 8; ++u) p[u * 256 + t] = v[u] * inv;
}

// ------------------------------------------------------------ launch ----
extern "C" void kernel_launch(void* const* d_in, const int* in_sizes, int n_in,
                              void* d_out, int out_size, void* d_ws, size_t ws_size,
                              hipStream_t stream) {
  const float* x       = (const float*)d_in[0];
  const float* ec1_w1  = (const float*)d_in[1];
  const float* ec1_bn1 = (const float*)d_in[2];
  const float* ec1_w2  = (const float*)d_in[3];
  const float* ec1_bn2 = (const float*)d_in[4];
  const float* ec2_w1  = (const float*)d_in[5];
  const float* ec2_bn1 = (const float*)d_in[6];
  const float* ec2_w2  = (const float*)d_in[7];
  const float* ec2_bn2 = (const float*)d_in[8];
  const float* ec3_w1  = (const float*)d_in[9];
  const float* ec3_bn1 = (const float*)d_in[10];
  const float* ec3_w2  = (const float*)d_in[11];
  const float* ec3_bn2 = (const float*)d_in[12];
  const float* emb_w   = (const float*)d_in[13];
  const float* q_w     = (const float*)d_in[14];
  const float* k_w     = (const float*)d_in[15];
  const float* v_w     = (const float*)d_in[16];
  const float* att_bn1 = (const float*)d_in[17];
  const float* ff_w1   = (const float*)d_in[18];
  const float* ff_w2   = (const float*)d_in[19];
  const float* att_bn2 = (const float*)d_in[20];
  const float* cb_w    = (const float*)d_in[21];
  const float* cb_bn   = (const float*)d_in[22];
  float* out = (float*)d_out;

  float* ws   = (float*)d_ws;
  float* sqb  = ws;                         // 16384
  int*   idxb = (int*)(ws + 16384);         // 524288 ints
  float* xc   = ws + 16384 + 524288;        // 3,145,728
  float* h    = xc + 3145728;               // 16,777,216
  float* qb   = h  + 16777216;              // 16,777,216
  float* kb   = qb + 16777216;              // 16,777,216 (later: ff1 out B,512,N)
  float* Sb   = kb + 16777216;              // 4,194,304 (N x N scratch)
  float* vb   = out;                        // v lives in d_out until final GEMM
  (void)in_sizes; (void)n_in; (void)out_size; (void)ws_size;

  const long bs192  = (long)192 * Np;
  const long bs1024 = (long)1024 * Np;
  const long bs512  = (long)512 * Np;

  // ---- EdgeConv 1 (CIN=3) ----
  sq_kernel<<<64, 256, 0, stream>>>(x, (long)3 * Np, 3, sqb);
  for (int b = 0; b < Bn; ++b) {
    gemm_kernel<true, false><<<dim3(16, 16, 1), 256, 0, stream>>>(
        x + (long)b * 3 * Np, Np, 0, x + (long)b * 3 * Np, Np, 0,
        Sb, Np, 0, Np, Np, 3, nullptr, nullptr, sqb + (long)b * Np, 0, 0);
    topk_kernel<<<Np, 64, 0, stream>>>(Sb, idxb + (long)b * Np * KNN);
  }
  edgeconv_kernel<3><<<dim3(Np, Bn), 64, 0, stream>>>(
      x, (long)3 * Np, idxb, ec1_w1, ec1_bn1, ec1_w2, ec1_bn2, xc, bs192);

  // ---- EdgeConv 2 (CIN=64, input f1 = xc[:,0:64,:]) ----
  sq_kernel<<<64, 256, 0, stream>>>(xc, bs192, 64, sqb);
  for (int b = 0; b < Bn; ++b) {
    gemm_kernel<true, false><<<dim3(16, 16, 1), 256, 0, stream>>>(
        xc + (long)b * bs192, Np, 0, xc + (long)b * bs192, Np, 0,
        Sb, Np, 0, Np, Np, 64, nullptr, nullptr, sqb + (long)b * Np, 0, 0);
    topk_kernel<<<Np, 64, 0, stream>>>(Sb, idxb + (long)b * Np * KNN);
  }
  edgeconv_kernel<64><<<dim3(Np, Bn), 64, 0, stream>>>(
      xc, bs192, idxb, ec2_w1, ec2_bn1, ec2_w2, ec2_bn2, xc + 64 * Np, bs192);

  // ---- EdgeConv 3 (CIN=64, input f2 = xc[:,64:128,:]) ----
  sq_kernel<<<64, 256, 0, stream>>>(xc + 64 * Np, bs192, 64, sqb);
  for (int b = 0; b < Bn; ++b) {
    gemm_kernel<true, false><<<dim3(16, 16, 1), 256, 0, stream>>>(
        xc + (long)b * bs192 + 64 * Np, Np, 0, xc + (long)b * bs192 + 64 * Np, Np, 0,
        Sb, Np, 0, Np, Np, 64, nullptr, nullptr, sqb + (long)b * Np, 0, 0);
    topk_kernel<<<Np, 64, 0, stream>>>(Sb, idxb + (long)b * Np * KNN);
  }
  edgeconv_kernel<64><<<dim3(Np, Bn), 64, 0, stream>>>(
      xc + 64 * Np, bs192, idxb, ec3_w1, ec3_bn1, ec3_w2, ec3_bn2, xc + 128 * Np, bs192);

  // ---- embedding: h = emb_w (1024x192) @ xc ----
  gemm_kernel<false, false><<<dim3(16, 8, Bn), 256, 0, stream>>>(
      emb_w, 192, 0, xc, Np, bs192, h, Np, bs1024,
      1024, Np, 192, nullptr, nullptr, nullptr, 0, 0);

  // ---- q, k, v ----
  gemm_kernel<false, false><<<dim3(16, 8, Bn), 256, 0, stream>>>(
      q_w, 1024, 0, h, Np, bs1024, qb, Np, bs1024, 1024, Np, 1024,
      nullptr, nullptr, nullptr, 0, 0);
  gemm_kernel<false, false><<<dim3(16, 8, Bn), 256, 0, stream>>>(
      k_w, 1024, 0, h, Np, bs1024, kb, Np, bs1024, 1024, Np, 1024,
      nullptr, nullptr, nullptr, 0, 0);
  gemm_kernel<false, false><<<dim3(16, 8, Bn), 256, 0, stream>>>(
      v_w, 1024, 0, h, Np, bs1024, vb, Np, bs1024, 1024, Np, 1024,
      nullptr, nullptr, nullptr, 0, 0);

  // ---- attention (per batch; S is N x N scratch) ----
  for (int b = 0; b < Bn; ++b) {
    gemm_kernel<true, false><<<dim3(16, 16, 1), 256, 0, stream>>>(
        qb + (long)b * bs1024, Np, 0, kb + (long)b * bs1024, Np, 0,
        Sb, Np, 0, Np, Np, 1024, nullptr, nullptr, nullptr, 0, 0);
    softmax_kernel<<<Np, 256, 0, stream>>>(Sb);
    // x_r = V @ P^T, then h = bn1(h + x_r)  (in-place residual)
    gemm_kernel<false, true><<<dim3(16, 8, 1), 256, 0, stream>>>(
        vb + (long)b * bs1024, Np, 0, Sb, Np, 0,
        h + (long)b * bs1024, Np, 0, 1024, Np, Np,
        att_bn1, h + (long)b * bs1024, nullptr, 0, 0);
  }

  // ---- FFN: ff1 (lrelu) into kb, ff2 + resid + bn2 into h ----
  gemm_kernel<false, false><<<dim3(16, 4, Bn), 256, 0, stream>>>(
      ff_w1, 1024, 0, h, Np, bs1024, kb, Np, bs512, 512, Np, 1024,
      nullptr, nullptr, nullptr, 0, 1);
  gemm_kernel<false, false><<<dim3(16, 8, Bn), 256, 0, stream>>>(
      ff_w2, 512, 0, kb, Np, bs512, h, Np, bs1024, 1024, Np, 512,
      att_bn2, h, nullptr, 0, 0);

  // ---- head: out = lrelu(bn(cb_w @ h)) ----
  gemm_kernel<false, false><<<dim3(16, 8, Bn), 256, 0, stream>>>(
      cb_w, 1024, 0, h, Np, bs1024, out, Np, bs1024, 1024, Np, 1024,
      cb_bn, nullptr, nullptr, 0, 1);
}

// Round 2
// 2636.972 us; speedup vs baseline: 4.7511x; 4.7511x over previous
//
#include <hip/hip_runtime.h>
#include <hip/hip_bf16.h>

constexpr int Bn  = 8;
constexpr int Np  = 2048;
constexpr int KNN = 32;

typedef __attribute__((ext_vector_type(8))) short bf16x8;
typedef __attribute__((ext_vector_type(4))) float f32x4;

__device__ static inline void gll16(const void* g, void* l) {
  __builtin_amdgcn_global_load_lds((const __attribute__((address_space(1))) void*)g,
                                   (__attribute__((address_space(3))) void*)l, 16, 0, 0);
}

__device__ static inline unsigned short f2bf(float x) {
  union { __hip_bfloat16 h; unsigned short u; } cv; cv.h = __float2bfloat16(x); return cv.u;
}
__device__ static inline float bf2f(unsigned short u) {
  union { __hip_bfloat16 h; unsigned short u; } cv; cv.u = u; return __bfloat162float(cv.h);
}

// ------------------------------------------------------------- helpers ----
__global__ __launch_bounds__(256)
void cvt_bf16_kernel(const float* __restrict__ s, __hip_bfloat16* __restrict__ d, int n) {
  int i = blockIdx.x * 256 + threadIdx.x;
  if (i < n) d[i] = __float2bfloat16(s[i]);
}

__global__ __launch_bounds__(256)
void xpose_kernel(const float* __restrict__ x, float* __restrict__ xt) {
  int i = blockIdx.x * 256 + threadIdx.x;   // over B*N
  int b = i >> 11, n = i & 2047;
  const float* p = x + (long)b * 3 * Np + n;
  xt[(long)i * 4 + 0] = p[0];
  xt[(long)i * 4 + 1] = p[Np];
  xt[(long)i * 4 + 2] = p[2 * Np];
  xt[(long)i * 4 + 3] = 0.f;
}

template<int C, int CP>
__global__ __launch_bounds__(256)
void sq_kernel(const float* __restrict__ f, float* __restrict__ out) {
  int i = blockIdx.x * 256 + threadIdx.x;   // over B*N
  const float* p = f + (long)i * CP;
  float s = 0.f;
#pragma unroll
  for (int c = 0; c < C; ++c) s += p[c] * p[c];
  out[i] = s;
}

// -------------------------------------------------- fp32 dist GEMM ----
// C[i][j] = sqB[j] - 2 * sum_k A[i][k]*B[j][k]   (A,B row-major [rows][K])
__global__ __launch_bounds__(256)
void dist_kernel(const float* __restrict__ A, int lda, long sA,
                 float* __restrict__ C, long sC,
                 const float* __restrict__ sqB, int Kd) {
  int bz = blockIdx.z;
  A += (long)bz * sA;
  C += (long)bz * sC;
  sqB += (long)bz * Np;
  int i0 = blockIdx.y * 128, j0 = blockIdx.x * 128;
  __shared__ float As[8][128];
  __shared__ float Bs[8][128];
  float acc[8][8];
#pragma unroll
  for (int a = 0; a < 8; ++a)
#pragma unroll
    for (int b2 = 0; b2 < 8; ++b2) acc[a][b2] = 0.f;
  int t = threadIdx.x;
  int tx = t & 15, ty = t >> 4;
  for (int k0 = 0; k0 < Kd; k0 += 8) {
    {
      int ii = t >> 1, kk = (t & 1) * 4;
#pragma unroll
      for (int u = 0; u < 4; ++u) {
        int kg = k0 + kk + u;
        As[kk + u][ii] = (kg < Kd) ? A[(long)(i0 + ii) * lda + kg] : 0.f;
        Bs[kk + u][ii] = (kg < Kd) ? A[(long)(j0 + ii) * lda + kg] : 0.f;
      }
    }
    __syncthreads();
#pragma unroll
    for (int kk = 0; kk < 8; ++kk) {
      float av[8], bv[8];
#pragma unroll
      for (int u = 0; u < 8; ++u) av[u] = As[kk][ty * 8 + u];
#pragma unroll
      for (int u = 0; u < 8; ++u) bv[u] = Bs[kk][tx * 8 + u];
#pragma unroll
      for (int a = 0; a < 8; ++a)
#pragma unroll
        for (int b2 = 0; b2 < 8; ++b2) acc[a][b2] += av[a] * bv[b2];
    }
    __syncthreads();
  }
#pragma unroll
  for (int a = 0; a < 8; ++a) {
    int i = i0 + ty * 8 + a;
#pragma unroll
    for (int b2 = 0; b2 < 8; ++b2) {
      int j = j0 + tx * 8 + b2;
      C[(long)i * Np + j] = sqB[j] - 2.f * acc[a][b2];
    }
  }
}

// -------------------------------------------------------------- topk ----
__global__ __launch_bounds__(64)
void topk_kernel(const float* __restrict__ D, int* __restrict__ idxOut) {
  long row = (long)blockIdx.y * Np + blockIdx.x;
  const float* rowp = D + row * Np;
  int lane = threadIdx.x;
  float v[32];
#pragma unroll
  for (int j = 0; j < 32; ++j) v[j] = rowp[j * 64 + lane];
  unsigned removed = 0u;
  __shared__ int sel[KNN];
  for (int t = 0; t < KNN; ++t) {
    float bk = 3.4e38f; int bi = -1; unsigned bbit = 0u;
#pragma unroll
    for (int j = 0; j < 32; ++j) {
      int m = j * 64 + lane;
      bool live = !(removed & (1u << j));
      bool better = live && ((v[j] < bk) || (v[j] == bk && (unsigned)m < (unsigned)bi));
      if (better) { bk = v[j]; bi = m; bbit = 1u << j; }
    }
    float rk = bk; int ri = bi;
#pragma unroll
    for (int off = 32; off > 0; off >>= 1) {
      float ok = __shfl_xor(rk, off);
      int   oi = __shfl_xor(ri, off);
      if ((ok < rk) || (ok == rk && (unsigned)oi < (unsigned)ri)) { rk = ok; ri = oi; }
    }
    if (bi == ri) removed |= bbit;
    if (lane == 0) sel[t] = ri;
  }
  __syncthreads();
  if (lane < KNN) idxOut[row * KNN + lane] = sel[lane];
}

// ---------------------------------------------------------- edgeconv ----
// [N,C] layouts. One wave per point.
template<int CIN, int CP>
__global__ __launch_bounds__(64)
void edgeconv_kernel(const float* __restrict__ feat, const int* __restrict__ idx,
                     const float* __restrict__ w1, const float* __restrict__ bn1,
                     const float* __restrict__ w2, const float* __restrict__ bn2,
                     float* __restrict__ fout, __hip_bfloat16* __restrict__ xcseg) {
  int n = blockIdx.x, b = blockIdx.y;
  int lane = threadIdx.x;
  long pb = (long)b * Np;
  __shared__ float ctr[CIN];
  __shared__ int nb[KNN];
  __shared__ float nbr[KNN * CIN];
  __shared__ float h1s[64 * 33];
  if (lane < KNN) nb[lane] = idx[(pb + n) * KNN + lane];
  if (lane < CIN) ctr[lane] = feat[(pb + n) * CP + lane];
  __syncthreads();
  for (int t2 = lane; t2 < KNN * CIN; t2 += 64) {
    int k2 = t2 / CIN, c = t2 - k2 * CIN;
    nbr[t2] = feat[(pb + nb[k2]) * CP + c];
  }
  __syncthreads();
  int o = lane;
  const float* w1r = w1 + o * 2 * CIN;
  float base = 0.f;
#pragma unroll
  for (int c = 0; c < CIN; ++c) base += (w1r[CIN + c] - w1r[c]) * ctr[c];
  float a1[KNN];
#pragma unroll
  for (int k2 = 0; k2 < KNN; ++k2) a1[k2] = base;
  constexpr int CH = (CIN >= 8) ? 8 : CIN;
  for (int c0 = 0; c0 < CIN; c0 += CH) {
    float wv[CH];
#pragma unroll
    for (int u = 0; u < CH; ++u) wv[u] = w1r[c0 + u];
#pragma unroll
    for (int u = 0; u < CH; ++u)
#pragma unroll
      for (int k2 = 0; k2 < KNN; ++k2) a1[k2] += wv[u] * nbr[k2 * CIN + c0 + u];
  }
  {
    float sc = bn1[o] * rsqrtf(bn1[192 + o] + 1e-5f);
    float sh = bn1[64 + o] - bn1[128 + o] * sc;
#pragma unroll
    for (int k2 = 0; k2 < KNN; ++k2) {
      float x = a1[k2] * sc + sh;
      h1s[o * 33 + k2] = (x >= 0.f) ? x : 0.2f * x;
    }
  }
  __syncthreads();
  const float* w2r = w2 + o * 64;
  float a2[KNN];
#pragma unroll
  for (int k2 = 0; k2 < KNN; ++k2) a2[k2] = 0.f;
  for (int c0 = 0; c0 < 64; c0 += 8) {
    float wv[8];
#pragma unroll
    for (int u = 0; u < 8; ++u) wv[u] = w2r[c0 + u];
#pragma unroll
    for (int u = 0; u < 8; ++u)
#pragma unroll
      for (int k2 = 0; k2 < KNN; ++k2) a2[k2] += wv[u] * h1s[(c0 + u) * 33 + k2];
  }
  float sc = bn2[o] * rsqrtf(bn2[192 + o] + 1e-5f);
  float sh = bn2[64 + o] - bn2[128 + o] * sc;
  float mx = -3.4e38f;
#pragma unroll
  for (int k2 = 0; k2 < KNN; ++k2) {
    float x = a2[k2] * sc + sh;
    x = (x >= 0.f) ? x : 0.2f * x;
    mx = fmaxf(mx, x);
  }
  if (fout) fout[(pb + n) * 64 + o] = mx;
  xcseg[(pb + n) * 192 + o] = __float2bfloat16(mx);
}

// ------------------------------------------------------ bf16 TN GEMM ----
// D[m][n] = sum_k A[m][k]*B[n][k]; A: Ma x K, B: Nb x K (both k-contiguous bf16).
// Store out[n*ldc + m] (m contiguous). OUTF: 0 bf16, 1 fp32.
// BNMODE: 0 none, 1 channel = m, 2 channel = n. RESID: += R[n*ldc+m] (bf16).
template<int OUTF, int BNMODE, int RESID, int LRELU>
__global__ __launch_bounds__(256)
void gemm_tn(const __hip_bfloat16* __restrict__ A, int lda, long sA,
             const __hip_bfloat16* __restrict__ B, int ldb, long sB,
             void* __restrict__ Cv, int ldc, long sC,
             const __hip_bfloat16* __restrict__ R, long sR,
             const float* __restrict__ bn, int bnlen, int Kd) {
  int bz = blockIdx.z;
  A += (long)bz * sA;
  B += (long)bz * sB;
  __shared__ __hip_bfloat16 As[128 * 32];
  __shared__ __hip_bfloat16 Bs[128 * 32];
  int t = threadIdx.x, lane = t & 63, w = t >> 6;
  int wm = w & 1, wn = w >> 1;
  long i0 = (long)blockIdx.x * 128, j0 = (long)blockIdx.y * 128;
  f32x4 acc[4][4];
#pragma unroll
  for (int i = 0; i < 4; ++i)
#pragma unroll
    for (int j = 0; j < 4; ++j) acc[i][j] = f32x4{0.f, 0.f, 0.f, 0.f};

  int srow = w * 16 + (lane >> 2);
  int sch  = (lane & 3) * 8;
  const __hip_bfloat16* ga0 = A + (i0 + srow) * lda + sch;
  const __hip_bfloat16* ga1 = A + (i0 + 64 + srow) * lda + sch;
  const __hip_bfloat16* gb0 = B + (j0 + srow) * ldb + sch;
  const __hip_bfloat16* gb1 = B + (j0 + 64 + srow) * ldb + sch;
  __hip_bfloat16* la0 = As + (w * 16) * 32;
  __hip_bfloat16* la1 = As + (64 + w * 16) * 32;
  __hip_bfloat16* lb0 = Bs + (w * 16) * 32;
  __hip_bfloat16* lb1 = Bs + (64 + w * 16) * 32;
  const __hip_bfloat16* pa = As + (wm * 64 + (lane & 15)) * 32 + (lane >> 4) * 8;
  const __hip_bfloat16* pb = Bs + (wn * 64 + (lane & 15)) * 32 + (lane >> 4) * 8;

  for (int k0 = 0; k0 < Kd; k0 += 32) {
    gll16(ga0, la0);
    gll16(ga1, la1);
    gll16(gb0, lb0);
    gll16(gb1, lb1);
    ga0 += 32; ga1 += 32; gb0 += 32; gb1 += 32;
    __syncthreads();
    bf16x8 af[4], bfv[4];
#pragma unroll
    for (int i = 0; i < 4; ++i) af[i]  = *(const bf16x8*)(pa + i * 16 * 32);
#pragma unroll
    for (int j = 0; j < 4; ++j) bfv[j] = *(const bf16x8*)(pb + j * 16 * 32);
#pragma unroll
    for (int i = 0; i < 4; ++i)
#pragma unroll
      for (int j = 0; j < 4; ++j)
        acc[i][j] = __builtin_amdgcn_mfma_f32_16x16x32_bf16(af[i], bfv[j], acc[i][j], 0, 0, 0);
    __syncthreads();
  }

  int mlocal = (lane >> 4) * 4;
  int nlocal = lane & 15;
#pragma unroll
  for (int i = 0; i < 4; ++i) {
    long m0 = i0 + wm * 64 + i * 16 + mlocal;
    float bsc[4], bsh[4];
    if (BNMODE == 1) {
#pragma unroll
      for (int r = 0; r < 4; ++r) {
        long c = m0 + r;
        float sc = bn[c] * rsqrtf(bn[3 * bnlen + c] + 1e-5f);
        bsc[r] = sc;
        bsh[r] = bn[bnlen + c] - bn[2 * bnlen + c] * sc;
      }
    }
#pragma unroll
    for (int j = 0; j < 4; ++j) {
      long nn = j0 + wn * 64 + j * 16 + nlocal;
      float sc2 = 1.f, sh2 = 0.f;
      if (BNMODE == 2) {
        sc2 = bn[nn] * rsqrtf(bn[3 * bnlen + nn] + 1e-5f);
        sh2 = bn[bnlen + nn] - bn[2 * bnlen + nn] * sc2;
      }
      f32x4 v = acc[i][j];
      float o4[4];
      ushort4 rv;
      if (RESID) rv = *(const ushort4*)(R + (long)bz * sR + nn * ldc + m0);
#pragma unroll
      for (int r = 0; r < 4; ++r) {
        float x = v[r];
        if (RESID) x += bf2f(r == 0 ? rv.x : r == 1 ? rv.y : r == 2 ? rv.z : rv.w);
        if (BNMODE == 1) x = x * bsc[r] + bsh[r];
        if (BNMODE == 2) x = x * sc2 + sh2;
        if (LRELU) x = (x >= 0.f) ? x : 0.2f * x;
        o4[r] = x;
      }
      if (OUTF) {
        float* Cp = (float*)Cv + (long)bz * sC + nn * ldc + m0;
        *(float4*)Cp = make_float4(o4[0], o4[1], o4[2], o4[3]);
      } else {
        __hip_bfloat16* Cp = (__hip_bfloat16*)Cv + (long)bz * sC + nn * ldc + m0;
        ushort4 sv;
        sv.x = f2bf(o4[0]); sv.y = f2bf(o4[1]); sv.z = f2bf(o4[2]); sv.w = f2bf(o4[3]);
        *(ushort4*)Cp = sv;
      }
    }
  }
}

// ----------------------------------------------------------- softmax ----
__global__ __launch_bounds__(256)
void softmax_bf(__hip_bfloat16* __restrict__ S) {
  long row = (long)blockIdx.y * Np + blockIdx.x;
  __hip_bfloat16* p = S + row * Np;
  int t = threadIdx.x;
  const float scale = 0.03125f;  // 1/sqrt(1024)
  float v[8];
  float mx = -3.4e38f;
#pragma unroll
  for (int u = 0; u < 8; ++u) {
    v[u] = __bfloat162float(p[u * 256 + t]) * scale;
    mx = fmaxf(mx, v[u]);
  }
  __shared__ float red[4];
#pragma unroll
  for (int off = 32; off > 0; off >>= 1) mx = fmaxf(mx, __shfl_xor(mx, off));
  if ((t & 63) == 0) red[t >> 6] = mx;
  __syncthreads();
  mx = fmaxf(fmaxf(red[0], red[1]), fmaxf(red[2], red[3]));
  __syncthreads();
  float sum = 0.f;
#pragma unroll
  for (int u = 0; u < 8; ++u) { v[u] = __expf(v[u] - mx); sum += v[u]; }
#pragma unroll
  for (int off = 32; off > 0; off >>= 1) sum += __shfl_xor(sum, off);
  if ((t & 63) == 0) red[t >> 6] = sum;
  __syncthreads();
  sum = red[0] + red[1] + red[2] + red[3];
  float inv = 1.f / sum;
#pragma unroll
  for (int u = 0; u < 8; ++u) p[u * 256 + t] = __float2bfloat16(v[u] * inv);
}

// ------------------------------------------------------------ launch ----
extern "C" void kernel_launch(void* const* d_in, const int* in_sizes, int n_in,
                              void* d_out, int out_size, void* d_ws, size_t ws_size,
                              hipStream_t stream) {
  const float* x       = (const float*)d_in[0];
  const float* ec1_w1  = (const float*)d_in[1];
  const float* ec1_bn1 = (const float*)d_in[2];
  const float* ec1_w2  = (const float*)d_in[3];
  const float* ec1_bn2 = (const float*)d_in[4];
  const float* ec2_w1  = (const float*)d_in[5];
  const float* ec2_bn1 = (const float*)d_in[6];
  const float* ec2_w2  = (const float*)d_in[7];
  const float* ec2_bn2 = (const float*)d_in[8];
  const float* ec3_w1  = (const float*)d_in[9];
  const float* ec3_bn1 = (const float*)d_in[10];
  const float* ec3_w2  = (const float*)d_in[11];
  const float* ec3_bn2 = (const float*)d_in[12];
  const float* emb_w   = (const float*)d_in[13];
  const float* q_w     = (const float*)d_in[14];
  const float* k_w     = (const float*)d_in[15];
  const float* v_w     = (const float*)d_in[16];
  const float* att_bn1 = (const float*)d_in[17];
  const float* ff_w1   = (const float*)d_in[18];
  const float* ff_w2   = (const float*)d_in[19];
  const float* att_bn2 = (const float*)d_in[20];
  const float* cb_w    = (const float*)d_in[21];
  const float* cb_bn   = (const float*)d_in[22];
  float* out = (float*)d_out;
  (void)in_sizes; (void)n_in; (void)out_size; (void)ws_size;

  // ---- workspace layout ----
  float* ws  = (float*)d_ws;
  float* xt  = ws;                        // [B,N,4] fp32       65,536
  float* f1  = xt + 65536;                // [B,N,64] fp32   1,048,576
  float* f2  = f1 + 1048576;              // [B,N,64] fp32   1,048,576
  float* sqb = f2 + 1048576;              // [B,N]              16,384
  int*   idxb = (int*)(sqb + 16384);      // [B,N,32]          524,288
  __hip_bfloat16* xc  = (__hip_bfloat16*)(idxb + 524288);  // [B,N,192] bf16
  __hip_bfloat16* wts = xc + 3145728;     // converted weights, 5,439,488 bf16
  float* big = (float*)(wts + 5439488);   // phase A: dist fp32 [B,N,N] (134MB)
  __hip_bfloat16* hb  = (__hip_bfloat16*)big;     // phase B: h   [B,N,1024]
  __hip_bfloat16* qb  = hb + 16777216;            //          q   [B,N,1024]
  __hip_bfloat16* kb  = qb + 16777216;            //          k   [B,N,1024] (later ff1 out)
  __hip_bfloat16* vtb = kb + 16777216;            //          v^T [B,1024,N]
  __hip_bfloat16* Sb  = vtb + 16777216;           //          S/P [B,N,N] bf16
  float* dist = big;

  __hip_bfloat16* emb_wb = wts;
  __hip_bfloat16* q_wb   = wts + 196608;
  __hip_bfloat16* k_wb   = wts + 1245184;
  __hip_bfloat16* v_wb   = wts + 2293760;
  __hip_bfloat16* ff1_wb = wts + 3342336;
  __hip_bfloat16* ff2_wb = wts + 3866624;
  __hip_bfloat16* cb_wb  = wts + 4390912;

  const long sN1024 = (long)Np * 1024;
  const long sN512  = (long)Np * 512;
  const long sN192  = (long)Np * 192;
  const long sNN    = (long)Np * Np;

  // ---- weight conversion ----
  cvt_bf16_kernel<<<768,  256, 0, stream>>>(emb_w, emb_wb, 196608);
  cvt_bf16_kernel<<<4096, 256, 0, stream>>>(q_w,   q_wb,   1048576);
  cvt_bf16_kernel<<<4096, 256, 0, stream>>>(k_w,   k_wb,   1048576);
  cvt_bf16_kernel<<<4096, 256, 0, stream>>>(v_w,   v_wb,   1048576);
  cvt_bf16_kernel<<<2048, 256, 0, stream>>>(ff_w1, ff1_wb, 524288);
  cvt_bf16_kernel<<<2048, 256, 0, stream>>>(ff_w2, ff2_wb, 524288);
  cvt_bf16_kernel<<<4096, 256, 0, stream>>>(cb_w,  cb_wb,  1048576);

  // ---- transpose input ----
  xpose_kernel<<<64, 256, 0, stream>>>(x, xt);

  // ---- EdgeConv 1 ----
  sq_kernel<3, 4><<<64, 256, 0, stream>>>(xt, sqb);
  dist_kernel<<<dim3(16, 16, Bn), 256, 0, stream>>>(xt, 4, (long)Np * 4, dist, sNN, sqb, 3);
  topk_kernel<<<dim3(Np, Bn), 64, 0, stream>>>(dist, idxb);
  edgeconv_kernel<3, 4><<<dim3(Np, Bn), 64, 0, stream>>>(
      xt, idxb, ec1_w1, ec1_bn1, ec1_w2, ec1_bn2, f1, xc);

  // ---- EdgeConv 2 ----
  sq_kernel<64, 64><<<64, 256, 0, stream>>>(f1, sqb);
  dist_kernel<<<dim3(16, 16, Bn), 256, 0, stream>>>(f1, 64, (long)Np * 64, dist, sNN, sqb, 64);
  topk_kernel<<<dim3(Np, Bn), 64, 0, stream>>>(dist, idxb);
  edgeconv_kernel<64, 64><<<dim3(Np, Bn), 64, 0, stream>>>(
      f1, idxb, ec2_w1, ec2_bn1, ec2_w2, ec2_bn2, f2, xc + 64);

  // ---- EdgeConv 3 ----
  sq_kernel<64, 64><<<64, 256, 0, stream>>>(f2, sqb);
  dist_kernel<<<dim3(16, 16, Bn), 256, 0, stream>>>(f2, 64, (long)Np * 64, dist, sNN, sqb, 64);
  topk_kernel<<<dim3(Np, Bn), 64, 0, stream>>>(dist, idxb);
  edgeconv_kernel<64, 64><<<dim3(Np, Bn), 64, 0, stream>>>(
      f2, idxb, ec3_w1, ec3_bn1, ec3_w2, ec3_bn2, nullptr, xc + 128);

  // ---- emb: h[n][c] = emb_w @ xc ----
  gemm_tn<0, 0, 0, 0><<<dim3(8, 16, Bn), 256, 0, stream>>>(
      emb_wb, 192, 0, xc, 192, sN192, hb, 1024, sN1024, nullptr, 0, nullptr, 0, 192);

  // ---- q, k (as [n][c]), v (as [c][n]) ----
  gemm_tn<0, 0, 0, 0><<<dim3(8, 16, Bn), 256, 0, stream>>>(
      q_wb, 1024, 0, hb, 1024, sN1024, qb, 1024, sN1024, nullptr, 0, nullptr, 0, 1024);
  gemm_tn<0, 0, 0, 0><<<dim3(8, 16, Bn), 256, 0, stream>>>(
      k_wb, 1024, 0, hb, 1024, sN1024, kb, 1024, sN1024, nullptr, 0, nullptr, 0, 1024);
  gemm_tn<0, 0, 0, 0><<<dim3(16, 8, Bn), 256, 0, stream>>>(
      hb, 1024, sN1024, v_wb, 1024, 0, vtb, 2048, sN1024, nullptr, 0, nullptr, 0, 1024);

  // ---- scores S[n][m] = k[m]·q[n], softmax rows ----
  gemm_tn<0, 0, 0, 0><<<dim3(16, 16, Bn), 256, 0, stream>>>(
      kb, 1024, sN1024, qb, 1024, sN1024, Sb, 2048, sNN, nullptr, 0, nullptr, 0, 1024);
  softmax_bf<<<dim3(Np, Bn), 256, 0, stream>>>(Sb);

  // ---- x_r[n][c] = sum_m P[n][m] vt[c][m]; h = bn1(h + x_r) in place ----
  gemm_tn<0, 1, 1, 0><<<dim3(8, 16, Bn), 256, 0, stream>>>(
      vtb, 2048, sN1024, Sb, 2048, sNN, hb, 1024, sN1024, hb, sN1024, att_bn1, 1024, 2048);

  // ---- ff1 (lrelu) into qb ----
  gemm_tn<0, 0, 0, 1><<<dim3(4, 16, Bn), 256, 0, stream>>>(
      ff1_wb, 1024, 0, hb, 1024, sN1024, qb, 512, sN512, nullptr, 0, nullptr, 0, 1024);
  // ---- ff2 + resid + bn2, in place on h ----
  gemm_tn<0, 1, 1, 0><<<dim3(8, 16, Bn), 256, 0, stream>>>(
      ff2_wb, 512, 0, qb, 512, sN512, hb, 1024, sN1024, hb, sN1024, att_bn2, 1024, 512);

  // ---- head: out[o][n] fp32 = lrelu(bn(cb_w @ h)) ----
  gemm_tn<1, 2, 0, 1><<<dim3(16, 8, Bn), 256, 0, stream>>>(
      hb, 1024, sN1024, cb_wb, 1024, 0, out, 2048, sN1024, nullptr, 0, cb_bn, 1024, 1024);
}

// Round 3
// 1971.645 us; speedup vs baseline: 6.3544x; 1.3374x over previous
//
#include <hip/hip_runtime.h>
#include <hip/hip_bf16.h>

constexpr int Bn  = 8;
constexpr int Np  = 2048;
constexpr int KNN = 32;

typedef __attribute__((ext_vector_type(8))) short bf16x8;
typedef __attribute__((ext_vector_type(4))) float f32x4;

__device__ static inline void gll16(const void* g, void* l) {
  __builtin_amdgcn_global_load_lds((const __attribute__((address_space(1))) void*)g,
                                   (__attribute__((address_space(3))) void*)l, 16, 0, 0);
}

__device__ static inline unsigned short f2bf(float x) {
  union { __hip_bfloat16 h; unsigned short u; } cv; cv.h = __float2bfloat16(x); return cv.u;
}
__device__ static inline float bf2f(unsigned short u) {
  union { __hip_bfloat16 h; unsigned short u; } cv; cv.u = u; return __bfloat162float(cv.h);
}

// ------------------------------------------------------------- helpers ----
__global__ __launch_bounds__(256)
void cvt_bf16_kernel(const float* __restrict__ s, __hip_bfloat16* __restrict__ d, int n) {
  int i = blockIdx.x * 256 + threadIdx.x;
  if (i < n) d[i] = __float2bfloat16(s[i]);
}

__global__ __launch_bounds__(256)
void xpose_kernel(const float* __restrict__ x, float* __restrict__ xt) {
  int i = blockIdx.x * 256 + threadIdx.x;   // over B*N
  int b = i >> 11, n = i & 2047;
  const float* p = x + (long)b * 3 * Np + n;
  xt[(long)i * 4 + 0] = p[0];
  xt[(long)i * 4 + 1] = p[Np];
  xt[(long)i * 4 + 2] = p[2 * Np];
  xt[(long)i * 4 + 3] = 0.f;
}

template<int C, int CP>
__global__ __launch_bounds__(256)
void sq_kernel(const float* __restrict__ f, float* __restrict__ out) {
  int i = blockIdx.x * 256 + threadIdx.x;   // over B*N
  const float* p = f + (long)i * CP;
  float s = 0.f;
#pragma unroll
  for (int c = 0; c < C; ++c) s += p[c] * p[c];
  out[i] = s;
}

// -------------------------------------------------- fp32 dist GEMM ----
// C[i][j] = sqB[j] - 2 * sum_k A[i][k]*B[j][k]   (A,B row-major [rows][K])
__global__ __launch_bounds__(256)
void dist_kernel(const float* __restrict__ A, int lda, long sA,
                 float* __restrict__ C, long sC,
                 const float* __restrict__ sqB, int Kd) {
  int bz = blockIdx.z;
  A += (long)bz * sA;
  C += (long)bz * sC;
  sqB += (long)bz * Np;
  int i0 = blockIdx.y * 128, j0 = blockIdx.x * 128;
  __shared__ float As[8][128];
  __shared__ float Bs[8][128];
  float acc[8][8];
#pragma unroll
  for (int a = 0; a < 8; ++a)
#pragma unroll
    for (int b2 = 0; b2 < 8; ++b2) acc[a][b2] = 0.f;
  int t = threadIdx.x;
  int tx = t & 15, ty = t >> 4;
  for (int k0 = 0; k0 < Kd; k0 += 8) {
    {
      int ii = t >> 1, kk = (t & 1) * 4;
#pragma unroll
      for (int u = 0; u < 4; ++u) {
        int kg = k0 + kk + u;
        As[kk + u][ii] = (kg < Kd) ? A[(long)(i0 + ii) * lda + kg] : 0.f;
        Bs[kk + u][ii] = (kg < Kd) ? A[(long)(j0 + ii) * lda + kg] : 0.f;
      }
    }
    __syncthreads();
#pragma unroll
    for (int kk = 0; kk < 8; ++kk) {
      float av[8], bv[8];
#pragma unroll
      for (int u = 0; u < 8; ++u) av[u] = As[kk][ty * 8 + u];
#pragma unroll
      for (int u = 0; u < 8; ++u) bv[u] = Bs[kk][tx * 8 + u];
#pragma unroll
      for (int a = 0; a < 8; ++a)
#pragma unroll
        for (int b2 = 0; b2 < 8; ++b2) acc[a][b2] += av[a] * bv[b2];
    }
    __syncthreads();
  }
#pragma unroll
  for (int a = 0; a < 8; ++a) {
    int i = i0 + ty * 8 + a;
#pragma unroll
    for (int b2 = 0; b2 < 8; ++b2) {
      int j = j0 + tx * 8 + b2;
      C[(long)i * Np + j] = sqB[j] - 2.f * acc[a][b2];
    }
  }
}

// -------------------------------------------------------------- topk ----
// One wave per row. Keys packed (ordered_float_bits << 32) | index so a
// single u64 compare encodes (dist asc, index asc). Per-lane bitonic sort
// of 32 keys, LDS spill (interleaved, conflict-free), then 32 pop rounds
// with a two-phase u32 butterfly min. Output = index set (order-insensitive
// downstream; order still matches stable top_k).
__global__ __launch_bounds__(64)
void topk_kernel(const float* __restrict__ D, int* __restrict__ idxOut) {
  long row = (long)blockIdx.y * Np + blockIdx.x;
  const float* rowp = D + row * Np;
  int lane = threadIdx.x;
  __shared__ unsigned long long buf[64 * 33];  // [i][lane] interleaved + pad

  unsigned long long key[32];
  const float4* rp = (const float4*)(rowp + lane * 32);
#pragma unroll
  for (int j4 = 0; j4 < 8; ++j4) {
    float4 f4 = rp[j4];
    float fv[4] = {f4.x, f4.y, f4.z, f4.w};
#pragma unroll
    for (int u = 0; u < 4; ++u) {
      int m = lane * 32 + j4 * 4 + u;
      unsigned b = __float_as_uint(fv[u]);
      unsigned ou = (b & 0x80000000u) ? ~b : (b | 0x80000000u);
      key[j4 * 4 + u] = ((unsigned long long)ou << 32) | (unsigned)m;
    }
  }
  // bitonic sort ascending (compile-time unrolled network, 240 CE)
#pragma unroll
  for (int k = 2; k <= 32; k <<= 1) {
#pragma unroll
    for (int j = k >> 1; j > 0; j >>= 1) {
#pragma unroll
      for (int i = 0; i < 32; ++i) {
        int l = i ^ j;
        if (l > i) {
          bool up = ((i & k) == 0);
          unsigned long long a = key[i], c = key[l];
          bool swp = up ? (a > c) : (a < c);
          unsigned long long lo = swp ? c : a;
          unsigned long long hi = swp ? a : c;
          key[i] = lo; key[l] = hi;
        }
      }
    }
  }
  // spill sorted list (element-major: write i is 512B contiguous across wave)
#pragma unroll
  for (int i = 0; i < 32; ++i) buf[i * 64 + lane] = key[i];

  unsigned long long h = key[0];
  int p = 1;
  int res = 0;
  for (int t = 0; t < KNN; ++t) {
    unsigned hh = (unsigned)(h >> 32), hl = (unsigned)h;
    unsigned g = hh;
#pragma unroll
    for (int off = 32; off > 0; off >>= 1)
      g = min(g, (unsigned)__shfl_xor((int)g, off));
    unsigned lo = (hh == g) ? hl : 0xFFFFFFFFu;
#pragma unroll
    for (int off = 32; off > 0; off >>= 1)
      lo = min(lo, (unsigned)__shfl_xor((int)lo, off));
    if (lane == t) res = (int)lo;          // lo = winning index m
    if (hh == g && hl == lo) {             // unique winner refills its head
      h = buf[p * 64 + lane];
      ++p;
    }
  }
  if (lane < KNN) idxOut[row * KNN + lane] = res;
}

// ---------------------------------------------------------- edgeconv ----
// [N,C] layouts. One wave per point.
template<int CIN, int CP>
__global__ __launch_bounds__(64)
void edgeconv_kernel(const float* __restrict__ feat, const int* __restrict__ idx,
                     const float* __restrict__ w1, const float* __restrict__ bn1,
                     const float* __restrict__ w2, const float* __restrict__ bn2,
                     float* __restrict__ fout, __hip_bfloat16* __restrict__ xcseg) {
  int n = blockIdx.x, b = blockIdx.y;
  int lane = threadIdx.x;
  long pb = (long)b * Np;
  __shared__ float ctr[CIN];
  __shared__ int nb[KNN];
  __shared__ float nbr[KNN * CIN];
  __shared__ float h1s[64 * 33];
  if (lane < KNN) nb[lane] = idx[(pb + n) * KNN + lane];
  if (lane < CIN) ctr[lane] = feat[(pb + n) * CP + lane];
  __syncthreads();
  for (int t2 = lane; t2 < KNN * CIN; t2 += 64) {
    int k2 = t2 / CIN, c = t2 - k2 * CIN;
    nbr[t2] = feat[(pb + nb[k2]) * CP + c];
  }
  __syncthreads();
  int o = lane;
  const float* w1r = w1 + o * 2 * CIN;
  float base = 0.f;
#pragma unroll
  for (int c = 0; c < CIN; ++c) base += (w1r[CIN + c] - w1r[c]) * ctr[c];
  float a1[KNN];
#pragma unroll
  for (int k2 = 0; k2 < KNN; ++k2) a1[k2] = base;
  constexpr int CH = (CIN >= 8) ? 8 : CIN;
  for (int c0 = 0; c0 < CIN; c0 += CH) {
    float wv[CH];
#pragma unroll
    for (int u = 0; u < CH; ++u) wv[u] = w1r[c0 + u];
#pragma unroll
    for (int u = 0; u < CH; ++u)
#pragma unroll
      for (int k2 = 0; k2 < KNN; ++k2) a1[k2] += wv[u] * nbr[k2 * CIN + c0 + u];
  }
  {
    float sc = bn1[o] * rsqrtf(bn1[192 + o] + 1e-5f);
    float sh = bn1[64 + o] - bn1[128 + o] * sc;
#pragma unroll
    for (int k2 = 0; k2 < KNN; ++k2) {
      float x = a1[k2] * sc + sh;
      h1s[o * 33 + k2] = (x >= 0.f) ? x : 0.2f * x;
    }
  }
  __syncthreads();
  const float* w2r = w2 + o * 64;
  float a2[KNN];
#pragma unroll
  for (int k2 = 0; k2 < KNN; ++k2) a2[k2] = 0.f;
  for (int c0 = 0; c0 < 64; c0 += 8) {
    float wv[8];
#pragma unroll
    for (int u = 0; u < 8; ++u) wv[u] = w2r[c0 + u];
#pragma unroll
    for (int u = 0; u < 8; ++u)
#pragma unroll
      for (int k2 = 0; k2 < KNN; ++k2) a2[k2] += wv[u] * h1s[(c0 + u) * 33 + k2];
  }
  float sc = bn2[o] * rsqrtf(bn2[192 + o] + 1e-5f);
  float sh = bn2[64 + o] - bn2[128 + o] * sc;
  float mx = -3.4e38f;
#pragma unroll
  for (int k2 = 0; k2 < KNN; ++k2) {
    float x = a2[k2] * sc + sh;
    x = (x >= 0.f) ? x : 0.2f * x;
    mx = fmaxf(mx, x);
  }
  if (fout) fout[(pb + n) * 64 + o] = mx;
  xcseg[(pb + n) * 192 + o] = __float2bfloat16(mx);
}

// ------------------------------------------------------ bf16 TN GEMM ----
// D[m][n] = sum_k A[m][k]*B[n][k]; A: Ma x K, B: Nb x K (both k-contiguous bf16).
// Store out[n*ldc + m] (m contiguous). OUTF: 0 bf16, 1 fp32.
// BNMODE: 0 none, 1 channel = m, 2 channel = n. RESID: += R[n*ldc+m] (bf16).
template<int OUTF, int BNMODE, int RESID, int LRELU>
__global__ __launch_bounds__(256)
void gemm_tn(const __hip_bfloat16* __restrict__ A, int lda, long sA,
             const __hip_bfloat16* __restrict__ B, int ldb, long sB,
             void* __restrict__ Cv, int ldc, long sC,
             const __hip_bfloat16* __restrict__ R, long sR,
             const float* __restrict__ bn, int bnlen, int Kd) {
  int bz = blockIdx.z;
  A += (long)bz * sA;
  B += (long)bz * sB;
  __shared__ __hip_bfloat16 As[128 * 32];
  __shared__ __hip_bfloat16 Bs[128 * 32];
  int t = threadIdx.x, lane = t & 63, w = t >> 6;
  int wm = w & 1, wn = w >> 1;
  long i0 = (long)blockIdx.x * 128, j0 = (long)blockIdx.y * 128;
  f32x4 acc[4][4];
#pragma unroll
  for (int i = 0; i < 4; ++i)
#pragma unroll
    for (int j = 0; j < 4; ++j) acc[i][j] = f32x4{0.f, 0.f, 0.f, 0.f};

  int srow = w * 16 + (lane >> 2);
  int sch  = (lane & 3) * 8;
  const __hip_bfloat16* ga0 = A + (i0 + srow) * lda + sch;
  const __hip_bfloat16* ga1 = A + (i0 + 64 + srow) * lda + sch;
  const __hip_bfloat16* gb0 = B + (j0 + srow) * ldb + sch;
  const __hip_bfloat16* gb1 = B + (j0 + 64 + srow) * ldb + sch;
  __hip_bfloat16* la0 = As + (w * 16) * 32;
  __hip_bfloat16* la1 = As + (64 + w * 16) * 32;
  __hip_bfloat16* lb0 = Bs + (w * 16) * 32;
  __hip_bfloat16* lb1 = Bs + (64 + w * 16) * 32;
  const __hip_bfloat16* pa = As + (wm * 64 + (lane & 15)) * 32 + (lane >> 4) * 8;
  const __hip_bfloat16* pb = Bs + (wn * 64 + (lane & 15)) * 32 + (lane >> 4) * 8;

  for (int k0 = 0; k0 < Kd; k0 += 32) {
    gll16(ga0, la0);
    gll16(ga1, la1);
    gll16(gb0, lb0);
    gll16(gb1, lb1);
    ga0 += 32; ga1 += 32; gb0 += 32; gb1 += 32;
    __syncthreads();
    bf16x8 af[4], bfv[4];
#pragma unroll
    for (int i = 0; i < 4; ++i) af[i]  = *(const bf16x8*)(pa + i * 16 * 32);
#pragma unroll
    for (int j = 0; j < 4; ++j) bfv[j] = *(const bf16x8*)(pb + j * 16 * 32);
#pragma unroll
    for (int i = 0; i < 4; ++i)
#pragma unroll
      for (int j = 0; j < 4; ++j)
        acc[i][j] = __builtin_amdgcn_mfma_f32_16x16x32_bf16(af[i], bfv[j], acc[i][j], 0, 0, 0);
    __syncthreads();
  }

  int mlocal = (lane >> 4) * 4;
  int nlocal = lane & 15;
#pragma unroll
  for (int i = 0; i < 4; ++i) {
    long m0 = i0 + wm * 64 + i * 16 + mlocal;
    float bsc[4], bsh[4];
    if (BNMODE == 1) {
#pragma unroll
      for (int r = 0; r < 4; ++r) {
        long c = m0 + r;
        float sc = bn[c] * rsqrtf(bn[3 * bnlen + c] + 1e-5f);
        bsc[r] = sc;
        bsh[r] = bn[bnlen + c] - bn[2 * bnlen + c] * sc;
      }
    }
#pragma unroll
    for (int j = 0; j < 4; ++j) {
      long nn = j0 + wn * 64 + j * 16 + nlocal;
      float sc2 = 1.f, sh2 = 0.f;
      if (BNMODE == 2) {
        sc2 = bn[nn] * rsqrtf(bn[3 * bnlen + nn] + 1e-5f);
        sh2 = bn[bnlen + nn] - bn[2 * bnlen + nn] * sc2;
      }
      f32x4 v = acc[i][j];
      float o4[4];
      ushort4 rv;
      if (RESID) rv = *(const ushort4*)(R + (long)bz * sR + nn * ldc + m0);
#pragma unroll
      for (int r = 0; r < 4; ++r) {
        float x = v[r];
        if (RESID) x += bf2f(r == 0 ? rv.x : r == 1 ? rv.y : r == 2 ? rv.z : rv.w);
        if (BNMODE == 1) x = x * bsc[r] + bsh[r];
        if (BNMODE == 2) x = x * sc2 + sh2;
        if (LRELU) x = (x >= 0.f) ? x : 0.2f * x;
        o4[r] = x;
      }
      if (OUTF) {
        float* Cp = (float*)Cv + (long)bz * sC + nn * ldc + m0;
        *(float4*)Cp = make_float4(o4[0], o4[1], o4[2], o4[3]);
      } else {
        __hip_bfloat16* Cp = (__hip_bfloat16*)Cv + (long)bz * sC + nn * ldc + m0;
        ushort4 sv;
        sv.x = f2bf(o4[0]); sv.y = f2bf(o4[1]); sv.z = f2bf(o4[2]); sv.w = f2bf(o4[3]);
        *(ushort4*)Cp = sv;
      }
    }
  }
}

// ----------------------------------------------------------- softmax ----
__global__ __launch_bounds__(256)
void softmax_bf(__hip_bfloat16* __restrict__ S) {
  long row = (long)blockIdx.y * Np + blockIdx.x;
  __hip_bfloat16* p = S + row * Np;
  int t = threadIdx.x;
  const float scale = 0.03125f;  // 1/sqrt(1024)
  float v[8];
  float mx = -3.4e38f;
#pragma unroll
  for (int u = 0; u < 8; ++u) {
    v[u] = __bfloat162float(p[u * 256 + t]) * scale;
    mx = fmaxf(mx, v[u]);
  }
  __shared__ float red[4];
#pragma unroll
  for (int off = 32; off > 0; off >>= 1) mx = fmaxf(mx, __shfl_xor(mx, off));
  if ((t & 63) == 0) red[t >> 6] = mx;
  __syncthreads();
  mx = fmaxf(fmaxf(red[0], red[1]), fmaxf(red[2], red[3]));
  __syncthreads();
  float sum = 0.f;
#pragma unroll
  for (int u = 0; u < 8; ++u) { v[u] = __expf(v[u] - mx); sum += v[u]; }
#pragma unroll
  for (int off = 32; off > 0; off >>= 1) sum += __shfl_xor(sum, off);
  if ((t & 63) == 0) red[t >> 6] = sum;
  __syncthreads();
  sum = red[0] + red[1] + red[2] + red[3];
  float inv = 1.f / sum;
#pragma unroll
  for (int u = 0; u < 8; ++u) p[u * 256 + t] = __float2bfloat16(v[u] * inv);
}

// ------------------------------------------------------------ launch ----
extern "C" void kernel_launch(void* const* d_in, const int* in_sizes, int n_in,
                              void* d_out, int out_size, void* d_ws, size_t ws_size,
                              hipStream_t stream) {
  const float* x       = (const float*)d_in[0];
  const float* ec1_w1  = (const float*)d_in[1];
  const float* ec1_bn1 = (const float*)d_in[2];
  const float* ec1_w2  = (const float*)d_in[3];
  const float* ec1_bn2 = (const float*)d_in[4];
  const float* ec2_w1  = (const float*)d_in[5];
  const float* ec2_bn1 = (const float*)d_in[6];
  const float* ec2_w2  = (const float*)d_in[7];
  const float* ec2_bn2 = (const float*)d_in[8];
  const float* ec3_w1  = (const float*)d_in[9];
  const float* ec3_bn1 = (const float*)d_in[10];
  const float* ec3_w2  = (const float*)d_in[11];
  const float* ec3_bn2 = (const float*)d_in[12];
  const float* emb_w   = (const float*)d_in[13];
  const float* q_w     = (const float*)d_in[14];
  const float* k_w     = (const float*)d_in[15];
  const float* v_w     = (const float*)d_in[16];
  const float* att_bn1 = (const float*)d_in[17];
  const float* ff_w1   = (const float*)d_in[18];
  const float* ff_w2   = (const float*)d_in[19];
  const float* att_bn2 = (const float*)d_in[20];
  const float* cb_w    = (const float*)d_in[21];
  const float* cb_bn   = (const float*)d_in[22];
  float* out = (float*)d_out;
  (void)in_sizes; (void)n_in; (void)out_size; (void)ws_size;

  // ---- workspace layout ----
  float* ws  = (float*)d_ws;
  float* xt  = ws;                        // [B,N,4] fp32       65,536
  float* f1  = xt + 65536;                // [B,N,64] fp32   1,048,576
  float* f2  = f1 + 1048576;              // [B,N,64] fp32   1,048,576
  float* sqb = f2 + 1048576;              // [B,N]              16,384
  int*   idxb = (int*)(sqb + 16384);      // [B,N,32]          524,288
  __hip_bfloat16* xc  = (__hip_bfloat16*)(idxb + 524288);  // [B,N,192] bf16
  __hip_bfloat16* wts = xc + 3145728;     // converted weights, 5,439,488 bf16
  float* big = (float*)(wts + 5439488);   // phase A: dist fp32 [B,N,N] (134MB)
  __hip_bfloat16* hb  = (__hip_bfloat16*)big;     // phase B: h   [B,N,1024]
  __hip_bfloat16* qb  = hb + 16777216;            //          q   [B,N,1024]
  __hip_bfloat16* kb  = qb + 16777216;            //          k   [B,N,1024] (later ff1 out)
  __hip_bfloat16* vtb = kb + 16777216;            //          v^T [B,1024,N]
  __hip_bfloat16* Sb  = vtb + 16777216;           //          S/P [B,N,N] bf16
  float* dist = big;

  __hip_bfloat16* emb_wb = wts;
  __hip_bfloat16* q_wb   = wts + 196608;
  __hip_bfloat16* k_wb   = wts + 1245184;
  __hip_bfloat16* v_wb   = wts + 2293760;
  __hip_bfloat16* ff1_wb = wts + 3342336;
  __hip_bfloat16* ff2_wb = wts + 3866624;
  __hip_bfloat16* cb_wb  = wts + 4390912;

  const long sN1024 = (long)Np * 1024;
  const long sN512  = (long)Np * 512;
  const long sN192  = (long)Np * 192;
  const long sNN    = (long)Np * Np;

  // ---- weight conversion ----
  cvt_bf16_kernel<<<768,  256, 0, stream>>>(emb_w, emb_wb, 196608);
  cvt_bf16_kernel<<<4096, 256, 0, stream>>>(q_w,   q_wb,   1048576);
  cvt_bf16_kernel<<<4096, 256, 0, stream>>>(k_w,   k_wb,   1048576);
  cvt_bf16_kernel<<<4096, 256, 0, stream>>>(v_w,   v_wb,   1048576);
  cvt_bf16_kernel<<<2048, 256, 0, stream>>>(ff_w1, ff1_wb, 524288);
  cvt_bf16_kernel<<<2048, 256, 0, stream>>>(ff_w2, ff2_wb, 524288);
  cvt_bf16_kernel<<<4096, 256, 0, stream>>>(cb_w,  cb_wb,  1048576);

  // ---- transpose input ----
  xpose_kernel<<<64, 256, 0, stream>>>(x, xt);

  // ---- EdgeConv 1 ----
  sq_kernel<3, 4><<<64, 256, 0, stream>>>(xt, sqb);
  dist_kernel<<<dim3(16, 16, Bn), 256, 0, stream>>>(xt, 4, (long)Np * 4, dist, sNN, sqb, 3);
  topk_kernel<<<dim3(Np, Bn), 64, 0, stream>>>(dist, idxb);
  edgeconv_kernel<3, 4><<<dim3(Np, Bn), 64, 0, stream>>>(
      xt, idxb, ec1_w1, ec1_bn1, ec1_w2, ec1_bn2, f1, xc);

  // ---- EdgeConv 2 ----
  sq_kernel<64, 64><<<64, 256, 0, stream>>>(f1, sqb);
  dist_kernel<<<dim3(16, 16, Bn), 256, 0, stream>>>(f1, 64, (long)Np * 64, dist, sNN, sqb, 64);
  topk_kernel<<<dim3(Np, Bn), 64, 0, stream>>>(dist, idxb);
  edgeconv_kernel<64, 64><<<dim3(Np, Bn), 64, 0, stream>>>(
      f1, idxb, ec2_w1, ec2_bn1, ec2_w2, ec2_bn2, f2, xc + 64);

  // ---- EdgeConv 3 ----
  sq_kernel<64, 64><<<64, 256, 0, stream>>>(f2, sqb);
  dist_kernel<<<dim3(16, 16, Bn), 256, 0, stream>>>(f2, 64, (long)Np * 64, dist, sNN, sqb, 64);
  topk_kernel<<<dim3(Np, Bn), 64, 0, stream>>>(dist, idxb);
  edgeconv_kernel<64, 64><<<dim3(Np, Bn), 64, 0, stream>>>(
      f2, idxb, ec3_w1, ec3_bn1, ec3_w2, ec3_bn2, nullptr, xc + 128);

  // ---- emb: h[n][c] = emb_w @ xc ----
  gemm_tn<0, 0, 0, 0><<<dim3(8, 16, Bn), 256, 0, stream>>>(
      emb_wb, 192, 0, xc, 192, sN192, hb, 1024, sN1024, nullptr, 0, nullptr, 0, 192);

  // ---- q, k (as [n][c]), v (as [c][n]) ----
  gemm_tn<0, 0, 0, 0><<<dim3(8, 16, Bn), 256, 0, stream>>>(
      q_wb, 1024, 0, hb, 1024, sN1024, qb, 1024, sN1024, nullptr, 0, nullptr, 0, 1024);
  gemm_tn<0, 0, 0, 0><<<dim3(8, 16, Bn), 256, 0, stream>>>(
      k_wb, 1024, 0, hb, 1024, sN1024, kb, 1024, sN1024, nullptr, 0, nullptr, 0, 1024);
  gemm_tn<0, 0, 0, 0><<<dim3(16, 8, Bn), 256, 0, stream>>>(
      hb, 1024, sN1024, v_wb, 1024, 0, vtb, 2048, sN1024, nullptr, 0, nullptr, 0, 1024);

  // ---- scores S[n][m] = k[m]·q[n], softmax rows ----
  gemm_tn<0, 0, 0, 0><<<dim3(16, 16, Bn), 256, 0, stream>>>(
      kb, 1024, sN1024, qb, 1024, sN1024, Sb, 2048, sNN, nullptr, 0, nullptr, 0, 1024);
  softmax_bf<<<dim3(Np, Bn), 256, 0, stream>>>(Sb);

  // ---- x_r[n][c] = sum_m P[n][m] vt[c][m]; h = bn1(h + x_r) in place ----
  gemm_tn<0, 1, 1, 0><<<dim3(8, 16, Bn), 256, 0, stream>>>(
      vtb, 2048, sN1024, Sb, 2048, sNN, hb, 1024, sN1024, hb, sN1024, att_bn1, 1024, 2048);

  // ---- ff1 (lrelu) into qb ----
  gemm_tn<0, 0, 0, 1><<<dim3(4, 16, Bn), 256, 0, stream>>>(
      ff1_wb, 1024, 0, hb, 1024, sN1024, qb, 512, sN512, nullptr, 0, nullptr, 0, 1024);
  // ---- ff2 + resid + bn2, in place on h ----
  gemm_tn<0, 1, 1, 0><<<dim3(8, 16, Bn), 256, 0, stream>>>(
      ff2_wb, 512, 0, qb, 512, sN512, hb, 1024, sN1024, hb, sN1024, att_bn2, 1024, 512);

  // ---- head: out[o][n] fp32 = lrelu(bn(cb_w @ h)) ----
  gemm_tn<1, 2, 0, 1><<<dim3(16, 8, Bn), 256, 0, stream>>>(
      hb, 1024, sN1024, cb_wb, 1024, 0, out, 2048, sN1024, nullptr, 0, cb_bn, 1024, 1024);
}